// Round 1
// baseline (679.492 us; speedup 1.0000x reference)
//
#include <hip/hip_runtime.h>

#define B_    8
#define CIN_  64
#define COUT_ 64
#define MID_  64
#define HH    256
#define WW    256
#define NP_   4
#define NL_   5

// Kernel 1: build per-batch combined conv weights into ws.
// Layout: wout[((b*COUT+co)*CIN+ci)*9 + (kh*3+kw)]
__global__ __launch_bounds__(256)
void build_weights(const float* __restrict__ h, const float* __restrict__ index,
                   const float* __restrict__ conv_weight,
                   const float* __restrict__ W_wp, const float* __restrict__ b_wp,
                   const float* __restrict__ W_wi, const float* __restrict__ b_wi,
                   const float* __restrict__ W_we, const float* __restrict__ b_we,
                   float* __restrict__ wout) {
    const int b   = blockIdx.y;
    const int ci0 = blockIdx.x * 8;   // 8 input channels per block
    const int tid = threadIdx.x;

    __shared__ float s_wpre[512];     // w_pre for ci in [ci0, ci0+8): 8*64 mids

    float hv[NP_], iv[NL_];
#pragma unroll
    for (int p = 0; p < NP_; ++p) hv[p] = h[b * NP_ + p];
#pragma unroll
    for (int l = 0; l < NL_; ++l) iv[l] = index[l];

    // Stage 1: w_pre[m] = b_wp[m]+b_wi[m] + h·W_wp[m,:] + index·W_wi[m,:]
    for (int t = tid; t < 512; t += 256) {
        int m = ci0 * MID_ + t;
        float acc = b_wp[m] + b_wi[m];
#pragma unroll
        for (int p = 0; p < NP_; ++p) acc += hv[p] * W_wp[m * NP_ + p];
#pragma unroll
        for (int l = 0; l < NL_; ++l) acc += iv[l] * W_wi[m * NL_ + l];
        s_wpre[t] = acc;
    }
    __syncthreads();

    // Stage 2: dw[b,ci,o9] = b_we[o9] + sum_mid w_pre[ci*64+mid]*W_we[o9,mid]
    // then weights = conv_weight + dw (with (B,CIN,COUT,3,3) -> (B,COUT,CIN,3,3) swap)
    for (int t = tid; t < 8 * 576; t += 256) {
        int cil = t / 576;
        int o9  = t - cil * 576;
        int ci  = ci0 + cil;
        float acc = b_we[o9];
        const float* wr  = W_we + o9 * MID_;
        const float* pre = s_wpre + cil * MID_;
#pragma unroll 8
        for (int mid = 0; mid < MID_; ++mid) acc += pre[mid] * wr[mid];
        int co = o9 / 9;
        int r  = o9 - co * 9;
        wout[((b * COUT_ + co) * CIN_ + ci) * 9 + r] =
            conv_weight[(co * CIN_ + ci) * 9 + r] + acc;
    }
}

// Kernel 2: direct conv. Each block: one b, 8 output channels, 4 rows x 256 cols.
__global__ __launch_bounds__(256)
void hyperconv(const float* __restrict__ x, const float* __restrict__ wAll,
               const float* __restrict__ conv_bias,
               const float* __restrict__ h, const float* __restrict__ index,
               const float* __restrict__ W_bp, const float* __restrict__ b_bp,
               const float* __restrict__ W_bi, const float* __restrict__ b_bi,
               float* __restrict__ out) {
    const int b   = blockIdx.z;
    const int co0 = blockIdx.y * 8;
    const int i0  = blockIdx.x * 4;
    const int j   = threadIdx.x;

    // Per-sample bias (uniform across threads; cheap)
    float bias[8];
#pragma unroll
    for (int c = 0; c < 8; ++c) {
        int co = co0 + c;
        float a = conv_bias[co] + b_bp[co] + b_bi[co];
#pragma unroll
        for (int p = 0; p < NP_; ++p) a += h[b * NP_ + p] * W_bp[co * NP_ + p];
#pragma unroll
        for (int l = 0; l < NL_; ++l) a += index[l] * W_bi[co * NL_ + l];
        bias[c] = a;
    }

    float acc[8][4];
#pragma unroll
    for (int c = 0; c < 8; ++c)
#pragma unroll
        for (int r = 0; r < 4; ++r) acc[c][r] = 0.f;

    const float* wb = wAll + (size_t)b * COUT_ * CIN_ * 9;
    const float* xb = x + (size_t)b * CIN_ * HH * WW;

    for (int ci = 0; ci < CIN_; ++ci) {
        const float* xp = xb + (size_t)ci * HH * WW;
        // 6 input rows x 3 shifted columns into registers, zero-padded borders.
        float xv[6][3];
#pragma unroll
        for (int rr = 0; rr < 6; ++rr) {
            int row = i0 - 1 + rr;
            bool rvalid = (unsigned)row < (unsigned)HH;   // uniform per block
            int rowc = rvalid ? row : 0;
#pragma unroll
            for (int dj = 0; dj < 3; ++dj) {
                int col = j - 1 + dj;
                bool cvalid = (unsigned)col < (unsigned)WW;
                int colc = cvalid ? col : 0;
                float v = xp[rowc * WW + colc];           // always in-bounds
                xv[rr][dj] = (rvalid && cvalid) ? v : 0.f;
            }
        }
#pragma unroll
        for (int c = 0; c < 8; ++c) {
            const float* wp = wb + ((co0 + c) * CIN_ + ci) * 9;  // uniform -> s_load
            float w[9];
#pragma unroll
            for (int k = 0; k < 9; ++k) w[k] = wp[k];
#pragma unroll
            for (int r = 0; r < 4; ++r)
#pragma unroll
                for (int di = 0; di < 3; ++di)
#pragma unroll
                    for (int dj = 0; dj < 3; ++dj)
                        acc[c][r] += w[di * 3 + dj] * xv[r + di][dj];
        }
    }

#pragma unroll
    for (int c = 0; c < 8; ++c) {
        float* op = out + (((size_t)(b * COUT_ + co0 + c) * HH + i0) * WW) + j;
#pragma unroll
        for (int r = 0; r < 4; ++r) op[r * WW] = acc[c][r] + bias[c];
    }
}

extern "C" void kernel_launch(void* const* d_in, const int* in_sizes, int n_in,
                              void* d_out, int out_size, void* d_ws, size_t ws_size,
                              hipStream_t stream) {
    const float* x           = (const float*)d_in[0];
    const float* h           = (const float*)d_in[1];
    const float* index       = (const float*)d_in[2];
    const float* conv_weight = (const float*)d_in[3];
    const float* conv_bias   = (const float*)d_in[4];
    const float* W_wp        = (const float*)d_in[5];
    const float* b_wp        = (const float*)d_in[6];
    const float* W_wi        = (const float*)d_in[7];
    const float* b_wi        = (const float*)d_in[8];
    const float* W_we        = (const float*)d_in[9];
    const float* b_we        = (const float*)d_in[10];
    const float* W_bp        = (const float*)d_in[11];
    const float* b_bp        = (const float*)d_in[12];
    const float* W_bi        = (const float*)d_in[13];
    const float* b_bi        = (const float*)d_in[14];

    float* out = (float*)d_out;
    float* wsW = (float*)d_ws;  // needs 8*64*64*9*4 = 1.18 MB

    build_weights<<<dim3(8, B_), 256, 0, stream>>>(
        h, index, conv_weight, W_wp, b_wp, W_wi, b_wi, W_we, b_we, wsW);

    hyperconv<<<dim3(HH / 4, COUT_ / 8, B_), 256, 0, stream>>>(
        x, wsW, conv_bias, h, index, W_bp, b_bp, W_bi, b_bi, out);
}

// Round 2
// 358.172 us; speedup vs baseline: 1.8971x; 1.8971x over previous
//
#include <hip/hip_runtime.h>
#include <hip/hip_bf16.h>
#include <string.h>

typedef short  short8  __attribute__((ext_vector_type(8)));
typedef float  f32x16  __attribute__((ext_vector_type(16)));
typedef unsigned short ushort_t;

#define B_    8
#define CIN_  64
#define COUT_ 64
#define MID_  64
#define HH    256
#define WW    256
#define NP_   4
#define NL_   5

#define TR 8            // output rows per block strip
#define TC 30           // output cols per tile
#define SR 10           // slab rows (TR + 2 halo)
#define SC 32           // slab cols (TC + 2 halo)
#define NJT 9           // col tiles: 9*30 = 270 >= 256
#define SLAB_ELE (SR*8*SC*8)     // 20480 ushort = 40960 B
#define W_ELE    (9*8*COUT_*8)   // 36864 ushort = 73728 B

// ---------------- Kernel 1: hypernet -> combined bf16 weights ----------------
// wsW layout: [b][khkw][ci>>3][co][ci&7]  (ci-unit-major for conflict-free MFMA frags)
__global__ __launch_bounds__(256)
void build_weights(const float* __restrict__ h, const float* __restrict__ index,
                   const float* __restrict__ conv_weight,
                   const float* __restrict__ W_wp, const float* __restrict__ b_wp,
                   const float* __restrict__ W_wi, const float* __restrict__ b_wi,
                   const float* __restrict__ W_we, const float* __restrict__ b_we,
                   ushort_t* __restrict__ wsW) {
    const int bb  = blockIdx.x >> 5;     // batch
    const int cig = blockIdx.x & 31;     // 2 input channels per block
    const int ci0 = cig * 2;
    const int tid = threadIdx.x;

    __shared__ float s_pre[2 * MID_];

    if (tid < 128) {
        const int cil = tid >> 6, mid = tid & 63;
        const int m = (ci0 + cil) * MID_ + mid;
        float acc = b_wp[m] + b_wi[m];
#pragma unroll
        for (int p = 0; p < NP_; ++p) acc += h[bb * NP_ + p] * W_wp[m * NP_ + p];
#pragma unroll
        for (int l = 0; l < NL_; ++l) acc += index[l] * W_wi[m * NL_ + l];
        s_pre[tid] = acc;
    }
    __syncthreads();

    for (int t = tid; t < 2 * 576; t += 256) {
        const int cil = t / 576;
        const int o9  = t - cil * 576;
        const float* wr = W_we + o9 * MID_;
        const float* pr = s_pre + cil * MID_;
        float a0 = b_we[o9], a1 = 0.f, a2 = 0.f, a3 = 0.f;
#pragma unroll 4
        for (int mid = 0; mid < MID_; mid += 4) {
            a0 += pr[mid]     * wr[mid];
            a1 += pr[mid + 1] * wr[mid + 1];
            a2 += pr[mid + 2] * wr[mid + 2];
            a3 += pr[mid + 3] * wr[mid + 3];
        }
        float acc = (a0 + a1) + (a2 + a3);
        const int co = o9 / 9;
        const int r  = o9 - co * 9;      // khkw
        const int ci = ci0 + cil;
        acc += conv_weight[(co * CIN_ + ci) * 9 + r];
        __hip_bfloat16 hb = __float2bfloat16(acc);
        ushort_t bits; __builtin_memcpy(&bits, &hb, 2);
        wsW[(((bb * 9 + r) * 8 + (ci >> 3)) * COUT_ + co) * 8 + (ci & 7)] = bits;
    }
}

// ---------------- Kernel 2: MFMA implicit-GEMM conv ----------------
__device__ __forceinline__ void stage_slab(const float* __restrict__ xb, int i0, int j0,
                                           ushort_t* __restrict__ sl, int t,
                                           int rr0, int rr1) {
    const int c  = t & 31;     // slab col
    const int pp = t >> 5;     // 0..7
    const int gc = j0 - 1 + c;
    const bool cok = (unsigned)gc < (unsigned)WW;
    const int gcc = cok ? gc : 0;
    unsigned int* sb = (unsigned int*)sl;
    for (int rr = rr0; rr < rr1; ++rr) {
        const int grow = i0 - 1 + rr;
        if ((unsigned)grow < (unsigned)HH) {
            const float* xr = xb + grow * WW + gcc;
#pragma unroll
            for (int it = 0; it < 4; ++it) {
                const int P = it * 8 + pp;      // ci-pair index, ci = 2P
                float f0 = xr[(P * 2)     * (HH * WW)];
                float f1 = xr[(P * 2 + 1) * (HH * WW)];
                f0 = cok ? f0 : 0.f;
                f1 = cok ? f1 : 0.f;
                __hip_bfloat162 h2 = __float22bfloat162_rn(make_float2(f0, f1));
                unsigned int u; __builtin_memcpy(&u, &h2, 4);
                sb[((rr * 8 + (P >> 2)) * 32 + c) * 4 + (P & 3)] = u;
            }
        } else {
#pragma unroll
            for (int it = 0; it < 4; ++it) {
                const int P = it * 8 + pp;
                sb[((rr * 8 + (P >> 2)) * 32 + c) * 4 + (P & 3)] = 0u;
            }
        }
    }
}

__global__ __launch_bounds__(512)
void hyperconv(const float* __restrict__ x, const ushort_t* __restrict__ wsW,
               const float* __restrict__ conv_bias,
               const float* __restrict__ h, const float* __restrict__ index,
               const float* __restrict__ W_bp, const float* __restrict__ b_bp,
               const float* __restrict__ W_bi, const float* __restrict__ b_bi,
               float* __restrict__ out) {
    __shared__ __align__(16) ushort_t Wl[W_ELE];
    __shared__ __align__(16) ushort_t Sx[2][SLAB_ELE];
    __shared__ float biasl[COUT_];

    const int tid   = threadIdx.x;
    const int bb    = blockIdx.x >> 5;
    const int strip = blockIdx.x & 31;
    const int i0    = strip * TR;
    const float* xb = x + bb * CIN_ * HH * WW;

    // --- stage weights (73728 B from L2) ---
    {
        const uint4* src = (const uint4*)(wsW + bb * W_ELE);
        uint4* dst = (uint4*)Wl;
        for (int i = tid; i < W_ELE / 8; i += 512) dst[i] = src[i];
    }
    // --- per-sample bias ---
    if (tid < COUT_) {
        const int co = tid;
        float a = conv_bias[co] + b_bp[co] + b_bi[co];
#pragma unroll
        for (int p = 0; p < NP_; ++p) a += h[bb * NP_ + p] * W_bp[co * NP_ + p];
#pragma unroll
        for (int l = 0; l < NL_; ++l) a += index[l] * W_bi[co * NL_ + l];
        biasl[co] = a;
    }
    // --- initial slab (all 8 waves, rr split) ---
    stage_slab(xb, i0, 0, &Sx[0][0], tid & 255, (tid >> 8) * 5, (tid >> 8) * 5 + 5);

    // --- consumer per-lane constants ---
    const int lane = tid & 63;
    const int wv   = tid >> 6;          // consumer wave 0..3
    const int n    = lane & 31;
    const int hl   = lane >> 5;
    int q[2], cc[2]; bool dead[2];
#pragma unroll
    for (int d = 0; d < 2; ++d) {
        const int flat = (2 * wv + d) * 32 + n;
        int qq = flat / 30;
        const int c2 = flat - qq * 30;
        dead[d] = (flat >= 240);
        if (qq > 7) qq = 7;
        q[d] = qq; cc[d] = c2;
    }
    const int baseA  = hl * 512 + n * 8;
    const int baseB0 = q[0] * 2048 + hl * 256 + cc[0] * 8;
    const int baseB1 = q[1] * 2048 + hl * 256 + cc[1] * 8;

    __syncthreads();

    for (int jt = 0; jt < NJT; ++jt) {
        const int buf = jt & 1;
        if (tid >= 256) {
            // producers: prefetch next tile
            if (jt + 1 < NJT)
                stage_slab(xb, i0, (jt + 1) * TC, &Sx[1 - buf][0], tid - 256, 0, SR);
        } else {
            // consumers: GEMM on current tile
            const int j0 = jt * TC;
            const ushort_t* sl = &Sx[buf][0];
            f32x16 a00 = {}, a10 = {}, a01 = {}, a11 = {};
#pragma unroll
            for (int kh = 0; kh < 3; ++kh)
#pragma unroll
                for (int kw = 0; kw < 3; ++kw) {
                    const int khkw = kh * 3 + kw;
#pragma unroll
                    for (int kk = 0; kk < 4; ++kk) {
                        short8 A0 = *(const short8*)&Wl[baseA + khkw * 4096 + kk * 1024];
                        short8 A1 = *(const short8*)&Wl[baseA + khkw * 4096 + kk * 1024 + 256];
                        short8 Bf0 = *(const short8*)&sl[baseB0 + kh * 2048 + kw * 8 + kk * 512];
                        short8 Bf1 = *(const short8*)&sl[baseB1 + kh * 2048 + kw * 8 + kk * 512];
                        a00 = __builtin_amdgcn_mfma_f32_32x32x16_bf16(A0, Bf0, a00, 0, 0, 0);
                        a10 = __builtin_amdgcn_mfma_f32_32x32x16_bf16(A1, Bf0, a10, 0, 0, 0);
                        a01 = __builtin_amdgcn_mfma_f32_32x32x16_bf16(A0, Bf1, a01, 0, 0, 0);
                        a11 = __builtin_amdgcn_mfma_f32_32x32x16_bf16(A1, Bf1, a11, 0, 0, 0);
                    }
                }
            // epilogue
#pragma unroll
            for (int d = 0; d < 2; ++d) {
                const f32x16& accL = d ? a01 : a00;
                const f32x16& accH = d ? a11 : a10;
                const bool valid = !dead[d] && (j0 + cc[d] < WW);
                if (valid) {
                    const int row  = i0 + q[d];
                    const int colg = j0 + cc[d];
                    float* op = out + (bb * COUT_) * (HH * WW) + row * WW + colg;
#pragma unroll
                    for (int r = 0; r < 16; ++r) {
                        const int coL = (r & 3) + 8 * (r >> 2) + 4 * hl;
                        op[coL * (HH * WW)] = accL[r] + biasl[coL];
                    }
#pragma unroll
                    for (int r = 0; r < 16; ++r) {
                        const int coH = (r & 3) + 8 * (r >> 2) + 4 * hl + 32;
                        op[coH * (HH * WW)] = accH[r] + biasl[coH];
                    }
                }
            }
        }
        __syncthreads();
    }
}

extern "C" void kernel_launch(void* const* d_in, const int* in_sizes, int n_in,
                              void* d_out, int out_size, void* d_ws, size_t ws_size,
                              hipStream_t stream) {
    const float* x           = (const float*)d_in[0];
    const float* h           = (const float*)d_in[1];
    const float* index       = (const float*)d_in[2];
    const float* conv_weight = (const float*)d_in[3];
    const float* conv_bias   = (const float*)d_in[4];
    const float* W_wp        = (const float*)d_in[5];
    const float* b_wp        = (const float*)d_in[6];
    const float* W_wi        = (const float*)d_in[7];
    const float* b_wi        = (const float*)d_in[8];
    const float* W_we        = (const float*)d_in[9];
    const float* b_we        = (const float*)d_in[10];
    const float* W_bp        = (const float*)d_in[11];
    const float* b_bp        = (const float*)d_in[12];
    const float* W_bi        = (const float*)d_in[13];
    const float* b_bi        = (const float*)d_in[14];

    float* out = (float*)d_out;
    ushort_t* wsW = (ushort_t*)d_ws;   // 8 * 36864 ushort = 589824 B

    build_weights<<<256, 256, 0, stream>>>(
        h, index, conv_weight, W_wp, b_wp, W_wi, b_wi, W_we, b_we, wsW);

    hyperconv<<<256, 512, 0, stream>>>(
        x, wsW, conv_bias, h, index, W_bp, b_bp, W_bi, b_bi, out);
}

// Round 3
// 330.518 us; speedup vs baseline: 2.0558x; 1.0837x over previous
//
#include <hip/hip_runtime.h>
#include <hip/hip_bf16.h>

typedef short  short8  __attribute__((ext_vector_type(8)));
typedef float  f32x16  __attribute__((ext_vector_type(16)));
typedef unsigned short ushort_t;

#define B_    8
#define CIN_  64
#define COUT_ 64
#define MID_  64
#define HH    256
#define WW    256
#define NP_   4
#define NL_   5

#define TR 8              // output rows per block strip
#define TC 32             // output cols per tile (line-aligned stores)
#define NJT 8             // 8*32 = 256 exact
#define SR 10             // slab rows (TR + 2 halo)
#define SCC 34            // slab cols (TC + 2 halo)
#define SLAB_U32 (SR*8*SCC*4)   // 10880 u32 = 43520 B
#define W_SHORTS (9*8*COUT_*8)  // 36864 shorts = 73728 B
#define NSTG 22                 // ceil(10880/512)

// ---------------- Kernel 1: hypernet -> combined bf16 weights ----------------
// wsW layout: [b][khkw][ci>>3][co][ci&7] shorts (same as verified round-2 layout)
__global__ __launch_bounds__(256)
void build_weights(const float* __restrict__ h, const float* __restrict__ index,
                   const float* __restrict__ conv_weight,
                   const float* __restrict__ W_wp, const float* __restrict__ b_wp,
                   const float* __restrict__ W_wi, const float* __restrict__ b_wi,
                   const float* __restrict__ W_we, const float* __restrict__ b_we,
                   ushort_t* __restrict__ wsW) {
    const int bb  = blockIdx.x / 9;       // batch
    const int ch  = blockIdx.x - bb * 9;  // o9 chunk of 64
    const int tid = threadIdx.x;

    __shared__ float pre_s[64 * 66];      // padded stride 66 (float2-aligned, 2-way banks)
    __shared__ float chunk_s[64 * 64];    // W_we chunk: 64 o9 x 64 mid

    float hv[NP_], iv[NL_];
#pragma unroll
    for (int p = 0; p < NP_; ++p) hv[p] = h[bb * NP_ + p];
#pragma unroll
    for (int l = 0; l < NL_; ++l) iv[l] = index[l];

    // pre[ci][mid] for all 64x64 (coalesced W_wp/W_wi reads)
#pragma unroll
    for (int k = 0; k < 16; ++k) {
        const int m = tid + k * 256;
        float a = b_wp[m] + b_wi[m];
#pragma unroll
        for (int p = 0; p < NP_; ++p) a += hv[p] * W_wp[m * NP_ + p];
#pragma unroll
        for (int l = 0; l < NL_; ++l) a += iv[l] * W_wi[m * NL_ + l];
        pre_s[(m >> 6) * 66 + (m & 63)] = a;
    }
    // stage W_we chunk (coalesced)
#pragma unroll
    for (int k = 0; k < 16; ++k) {
        const int f = tid + k * 256;
        chunk_s[f] = W_we[ch * 4096 + f];
    }
    __syncthreads();

    const int ci = tid & 63;
    const int g  = tid >> 6;   // 0..3, uniform per wave -> chunk reads broadcast
    float acc[16];
#pragma unroll
    for (int u = 0; u < 16; ++u) acc[u] = 0.f;

#pragma unroll
    for (int mid = 0; mid < 64; mid += 2) {
        const float2 pv = *(const float2*)&pre_s[ci * 66 + mid];
#pragma unroll
        for (int u = 0; u < 16; ++u) {
            const float2 wv = *(const float2*)&chunk_s[(g + 4 * u) * 64 + mid];
            acc[u] += pv.x * wv.x + pv.y * wv.y;
        }
    }

#pragma unroll
    for (int u = 0; u < 16; ++u) {
        const int o9 = ch * 64 + g + 4 * u;
        const int co = o9 / 9;
        const int r  = o9 - co * 9;
        const float val = acc[u] + b_we[o9] + conv_weight[(co * CIN_ + ci) * 9 + r];
        __hip_bfloat16 hb = __float2bfloat16(val);
        ushort_t bits; __builtin_memcpy(&bits, &hb, 2);
        wsW[(((bb * 9 + r) * 8 + (ci >> 3)) * COUT_ + co) * 8 + (ci & 7)] = bits;
    }
}

// ---------------- Kernel 2: MFMA implicit-GEMM conv ----------------
// Slab layout (u32, each = bf16 ci-pair): [r 10][g 8][c 34][p 4], ci = g*8 + 2p (+0/1)
__device__ __forceinline__ void load_tile(const float* __restrict__ xb, int i0, int j0,
                                          int tid, unsigned (&vals)[NSTG]) {
#pragma unroll
    for (int k = 0; k < NSTG; ++k) {
        const int s = tid + k * 512;
        unsigned v = 0u;
        if (s < SLAB_U32) {
            const int p  = s & 3;
            const int t2 = s >> 2;
            const int c  = t2 % SCC;
            const int t3 = t2 / SCC;      // r*8 + g
            const int g  = t3 & 7;
            const int r  = t3 >> 3;
            const int gr = i0 - 1 + r;
            const int gc = j0 - 1 + c;
            const int ci = g * 8 + p * 2;
            const bool ok = ((unsigned)gr < (unsigned)HH) && ((unsigned)gc < (unsigned)WW);
            const float* px = xb + ci * (HH * WW) + (ok ? (gr * WW + gc) : 0);
            float f0 = px[0];
            float f1 = px[HH * WW];
            if (!ok) { f0 = 0.f; f1 = 0.f; }
            const __hip_bfloat162 h2 = __float22bfloat162_rn(make_float2(f0, f1));
            __builtin_memcpy(&v, &h2, 4);
        }
        vals[k] = v;
    }
}

__global__ __launch_bounds__(512, 2)
void hyperconv(const float* __restrict__ x, const ushort_t* __restrict__ wsW,
               const float* __restrict__ conv_bias,
               const float* __restrict__ h, const float* __restrict__ index,
               const float* __restrict__ W_bp, const float* __restrict__ b_bp,
               const float* __restrict__ W_bi, const float* __restrict__ b_bi,
               float* __restrict__ out) {
    __shared__ __align__(16) ushort_t Wl[W_SHORTS];   // 73728 B
    __shared__ __align__(16) unsigned Slab[SLAB_U32]; // 43520 B
    __shared__ float biasl[COUT_];

    const int tid   = threadIdx.x;
    const int bb    = blockIdx.x >> 5;
    const int strip = blockIdx.x & 31;
    const int i0    = strip * TR;
    const float* xb = x + bb * CIN_ * HH * WW;

    // prefetch tile 0 into regs first (latency hidden under Wl/bias setup)
    unsigned vals[NSTG];
    load_tile(xb, i0, 0, tid, vals);

    // stage weights (L2/L3-resident, coalesced 16B)
    {
        const uint4* src = (const uint4*)(wsW + bb * W_SHORTS);
        uint4* dst = (uint4*)Wl;
        for (int i = tid; i < W_SHORTS / 8; i += 512) dst[i] = src[i];
    }
    // per-sample bias
    if (tid < COUT_) {
        const int co = tid;
        float a = conv_bias[co] + b_bp[co] + b_bi[co];
#pragma unroll
        for (int p = 0; p < NP_; ++p) a += h[bb * NP_ + p] * W_bp[co * NP_ + p];
#pragma unroll
        for (int l = 0; l < NL_; ++l) a += index[l] * W_bi[co * NL_ + l];
        biasl[co] = a;
    }

    const int lane = tid & 63;
    const int wv   = tid >> 6;     // 0..7 -> output row within strip
    const int n    = lane & 31;    // output col within tile / co for A
    const int hl   = lane >> 5;    // k-half

    for (int jt = 0; jt < NJT; ++jt) {
        __syncthreads();   // iter 0: Wl/bias ready; later: prior slab reads done
        // write current tile regs -> slab (waits the global loads here)
#pragma unroll
        for (int k = 0; k < NSTG; ++k) {
            const int s = tid + k * 512;
            if (s < SLAB_U32) Slab[s] = vals[k];
        }
        // issue next tile's loads (drain at NEXT iteration's first barrier)
        if (jt + 1 < NJT) load_tile(xb, i0, (jt + 1) * TC, tid, vals);
        __syncthreads();   // slab visible

        f32x16 a0 = {}, a1 = {};
        const ushort_t* sl = (const ushort_t*)Slab;
#pragma unroll
        for (int kh = 0; kh < 3; ++kh)
#pragma unroll
            for (int kw = 0; kw < 3; ++kw) {
                const int khkw = kh * 3 + kw;
#pragma unroll
                for (int kk = 0; kk < 4; ++kk) {
                    const int gA = khkw * 8 + 2 * kk + hl;
                    const short8 A0 = *(const short8*)&Wl[(gA * 64 + n) * 8];
                    const short8 A1 = *(const short8*)&Wl[(gA * 64 + n + 32) * 8];
                    const int gB = ((wv + kh) * 8 + 2 * kk + hl) * SCC + (n + kw);
                    const short8 Bf = *(const short8*)&sl[gB * 8];
                    a0 = __builtin_amdgcn_mfma_f32_32x32x16_bf16(A0, Bf, a0, 0, 0, 0);
                    a1 = __builtin_amdgcn_mfma_f32_32x32x16_bf16(A1, Bf, a1, 0, 0, 0);
                }
            }

        // epilogue: fully line-aligned stores
        const int j0 = jt * TC;
        float* op = out + (size_t)(bb * COUT_) * (HH * WW) + (i0 + wv) * WW + j0 + n;
#pragma unroll
        for (int r = 0; r < 16; ++r) {
            const int co = (r & 3) + 8 * (r >> 2) + 4 * hl;
            op[co * (HH * WW)] = a0[r] + biasl[co];
        }
#pragma unroll
        for (int r = 0; r < 16; ++r) {
            const int co = (r & 3) + 8 * (r >> 2) + 4 * hl + 32;
            op[co * (HH * WW)] = a1[r] + biasl[co];
        }
    }
}

extern "C" void kernel_launch(void* const* d_in, const int* in_sizes, int n_in,
                              void* d_out, int out_size, void* d_ws, size_t ws_size,
                              hipStream_t stream) {
    const float* x           = (const float*)d_in[0];
    const float* h           = (const float*)d_in[1];
    const float* index       = (const float*)d_in[2];
    const float* conv_weight = (const float*)d_in[3];
    const float* conv_bias   = (const float*)d_in[4];
    const float* W_wp        = (const float*)d_in[5];
    const float* b_wp        = (const float*)d_in[6];
    const float* W_wi        = (const float*)d_in[7];
    const float* b_wi        = (const float*)d_in[8];
    const float* W_we        = (const float*)d_in[9];
    const float* b_we        = (const float*)d_in[10];
    const float* W_bp        = (const float*)d_in[11];
    const float* b_bp        = (const float*)d_in[12];
    const float* W_bi        = (const float*)d_in[13];
    const float* b_bi        = (const float*)d_in[14];

    float* out = (float*)d_out;
    ushort_t* wsW = (ushort_t*)d_ws;   // 8 * 36864 * 2 = 589824 B

    build_weights<<<72, 256, 0, stream>>>(
        h, index, conv_weight, W_wp, b_wp, W_wi, b_wi, W_we, b_we, wsW);

    hyperconv<<<256, 512, 0, stream>>>(
        x, wsW, conv_bias, h, index, W_bp, b_bp, W_bi, b_bi, out);
}